// Round 7
// baseline (585.588 us; speedup 1.0000x reference)
//
#include <hip/hip_runtime.h>

#define NPTS 32768
#define CH 64
#define KNN 16
#define NE (NPTS*KNN)
#define EPS 1e-5f
#define NREP 32

// raw stats groups: NREP replicas x 128 floats; sums at [c], sumsq at [64+c]
#define G_P   0
#define G_BN1 (1*NREP*128)
#define G_W1  (2*NREP*128)
#define G_W2  (3*NREP*128)
#define G_BN2 (4*NREP*128)
#define G_BN3 (5*NREP*128)
#define STATS_FLOATS (6*NREP*128)

// finalized scale/shift: 128 floats each: [sc 0..63][sh 64..127]
#define F_P   (STATS_FLOATS + 0*128)
#define F_BN1 (STATS_FLOATS + 1*128)
#define F_W1  (STATS_FLOATS + 2*128)
#define F_W2  (STATS_FLOATS + 3*128)
#define F_BN2 (STATS_FLOATS + 4*128)
#define F_BN3 (STATS_FLOATS + 5*128)

#define OFF_T1  (STATS_FLOATS + 1024)
#define SZ_NC   (NPTS*CH)
#define OFF_K   (OFF_T1 + SZ_NC)
#define OFF_Q   (OFF_K + SZ_NC)
#define OFF_V   (OFF_Q + SZ_NC)
#define OFF_A2  (OFF_V + SZ_NC)
#define OFF_OUT (OFF_A2 + NE*8)
#define OFF_U   (OFF_OUT + SZ_NC)   /* NE*4 floats; shared with H3 (dead by then) */
#define OFF_H3  OFF_U

__device__ __forceinline__ float frelu(float x){ return fmaxf(x, 0.f); }

// ---------- finalize up to two stats groups -> [sc|sh] ----------
__global__ __launch_bounds__(128) void k_fin(
    const float* __restrict__ gA, float invA, const float* __restrict__ gmA,
    const float* __restrict__ btA, float* __restrict__ outA, int nchA,
    const float* __restrict__ gB, float invB, const float* __restrict__ gmB,
    const float* __restrict__ btB, float* __restrict__ outB, int nchB)
{
    __shared__ float s_tmp[128];
    const int tid = threadIdx.x;
    const float* g; float inv; const float* gm; const float* bt; float* o; int nch;
    if (blockIdx.x == 0) { g=gA; inv=invA; gm=gmA; bt=btA; o=outA; nch=nchA; }
    else { if (!outB) return; g=gB; inv=invB; gm=gmB; bt=btB; o=outB; nch=nchB; }
    float t = 0.f;
    #pragma unroll
    for (int r=0;r<NREP;++r) t += g[r*128+tid];
    s_tmp[tid] = t;
    __syncthreads();
    if (tid < 64) {
        if (tid < nch) {
            float m = s_tmp[tid]*inv;
            float v = s_tmp[64+tid]*inv - m*m;
            float s = gm[tid]*rsqrtf(v+EPS);
            o[tid] = s; o[64+tid] = bt[tid] - m*s;
        } else { o[tid]=0.f; o[64+tid]=0.f; }
    }
}

// ---------- u = rel @ p1_w^T + p1_b per edge (stored), plus p-bn stats ----------
__global__ __launch_bounds__(256) void k_pstats_u(
    const float* __restrict__ pos, const int* __restrict__ esrc,
    const float* __restrict__ p1w, const float* __restrict__ p1b,
    float4* __restrict__ u4, float* __restrict__ gstat)
{
    __shared__ float red[4][6];
    const int tid = threadIdx.x;
    const float w0=p1w[0],w1=p1w[1],w2=p1w[2],w3=p1w[3],w4=p1w[4],w5=p1w[5],w6=p1w[6],w7=p1w[7],w8=p1w[8];
    const float b0=p1b[0],b1=p1b[1],b2=p1b[2];
    const int e = blockIdx.x*256 + tid;
    const int sj = esrc[e]; const int d = e >> 4;
    float ax = pos[3*sj]-pos[3*d], ay = pos[3*sj+1]-pos[3*d+1], az = pos[3*sj+2]-pos[3*d+2];
    float u0 = w0*ax+w1*ay+w2*az+b0;
    float u1 = w3*ax+w4*ay+w5*az+b1;
    float u2 = w6*ax+w7*ay+w8*az+b2;
    u4[e] = make_float4(u0,u1,u2,0.f);
    float s0=u0,s1=u1,s2=u2,q0=u0*u0,q1=u1*u1,q2=u2*u2;
    #pragma unroll
    for (int m=32;m>=1;m>>=1){
        s0+=__shfl_xor(s0,m); s1+=__shfl_xor(s1,m); s2+=__shfl_xor(s2,m);
        q0+=__shfl_xor(q0,m); q1+=__shfl_xor(q1,m); q2+=__shfl_xor(q2,m);
    }
    const int wv = tid>>6;
    if ((tid&63)==0){ red[wv][0]=s0; red[wv][1]=s1; red[wv][2]=s2;
                      red[wv][3]=q0; red[wv][4]=q1; red[wv][5]=q2; }
    __syncthreads();
    float* g = gstat + (blockIdx.x & (NREP-1))*128;
    if (tid < 3)      atomicAdd(&g[tid],        red[0][tid]+red[1][tid]+red[2][tid]+red[3][tid]);
    else if (tid < 6) atomicAdd(&g[64+(tid-3)], red[0][tid]+red[1][tid]+red[2][tid]+red[3][tid]);
}

// ---------- [N,64]@W^T, 16 out-ch/block, streaming input (no register array) ----------
// grid 512: by = bid>>7 channel slice, rb = bid&127 rows
__global__ __launch_bounds__(256) void k_gemm64(
    const float* __restrict__ in, const float* __restrict__ W,
    float* __restrict__ out,
    const float* __restrict__ fbn, int applyBn,
    float* __restrict__ gstat)
{
    __shared__ float Wt[CH*16];     // Wt[i*16 + r] = W[c0+r][i]
    __shared__ float4 fL[32];
    __shared__ float red[4][32];
    const int tid = threadIdx.x;
    const int wv = tid >> 6;
    const int by = blockIdx.x >> 7;
    const int rb = blockIdx.x & 127;
    const int c0 = by*16;
    // stage LDS-linear (no write conflicts): idx = ch*256+tid; i=idx>>4; r=idx&15
    #pragma unroll
    for (int ch=0; ch<4; ++ch){
        const int idx = ch*256 + tid;
        Wt[idx] = W[(size_t)(c0 + (idx & 15))*CH + (idx >> 4)];
    }
    if (applyBn && tid < 32) fL[tid] = ((const float4*)fbn)[tid];
    __syncthreads();

    const int row = rb*256 + tid;
    const float4* iv = (const float4*)(in + (size_t)row*CH);
    const float4* Wt4 = (const float4*)Wt;
    float4 a0 = make_float4(0,0,0,0), a1 = a0, a2 = a0, a3 = a0;
    #pragma unroll
    for (int j=0;j<16;++j){
        float4 x4 = iv[j];
        if (applyBn){
            float4 s4 = fL[j], h4 = fL[16+j];
            x4.x = frelu(x4.x*s4.x+h4.x); x4.y = frelu(x4.y*s4.y+h4.y);
            x4.z = frelu(x4.z*s4.z+h4.z); x4.w = frelu(x4.w*s4.w+h4.w);
        }
        #define GSTEP(comp, xv) { \
            float4 wq0 = Wt4[(4*j+comp)*4+0], wq1 = Wt4[(4*j+comp)*4+1]; \
            float4 wq2 = Wt4[(4*j+comp)*4+2], wq3 = Wt4[(4*j+comp)*4+3]; \
            a0.x += (xv)*wq0.x; a0.y += (xv)*wq0.y; a0.z += (xv)*wq0.z; a0.w += (xv)*wq0.w; \
            a1.x += (xv)*wq1.x; a1.y += (xv)*wq1.y; a1.z += (xv)*wq1.z; a1.w += (xv)*wq1.w; \
            a2.x += (xv)*wq2.x; a2.y += (xv)*wq2.y; a2.z += (xv)*wq2.z; a2.w += (xv)*wq2.w; \
            a3.x += (xv)*wq3.x; a3.y += (xv)*wq3.y; a3.z += (xv)*wq3.z; a3.w += (xv)*wq3.w; }
        GSTEP(0, x4.x) GSTEP(1, x4.y) GSTEP(2, x4.z) GSTEP(3, x4.w)
        #undef GSTEP
    }
    float4* ov = (float4*)(out + (size_t)row*CH + c0);
    ov[0]=a0; ov[1]=a1; ov[2]=a2; ov[3]=a3;
    #define STATQ(q, a) { \
        float4 s = a; \
        float4 sq = make_float4(s.x*s.x, s.y*s.y, s.z*s.z, s.w*s.w); \
        _Pragma("unroll") \
        for (int m=32;m>=1;m>>=1){ \
            s.x+=__shfl_xor(s.x,m); s.y+=__shfl_xor(s.y,m); \
            s.z+=__shfl_xor(s.z,m); s.w+=__shfl_xor(s.w,m); \
            sq.x+=__shfl_xor(sq.x,m); sq.y+=__shfl_xor(sq.y,m); \
            sq.z+=__shfl_xor(sq.z,m); sq.w+=__shfl_xor(sq.w,m); } \
        if ((tid&63)==0){ \
            red[wv][q*4+0]=s.x; red[wv][q*4+1]=s.y; red[wv][q*4+2]=s.z; red[wv][q*4+3]=s.w; \
            red[wv][16+q*4+0]=sq.x; red[wv][16+q*4+1]=sq.y; red[wv][16+q*4+2]=sq.z; red[wv][16+q*4+3]=sq.w; } }
    STATQ(0, a0) STATQ(1, a1) STATQ(2, a2) STATQ(3, a3)
    #undef STATQ
    __syncthreads();
    if (tid < 32) {
        float t = red[0][tid]+red[1][tid]+red[2][tid]+red[3][tid];
        int dstc = (tid<16) ? (c0+tid) : (64 + c0 + (tid-16));
        atomicAdd(&gstat[(blockIdx.x & (NREP-1))*128 + dstc], t);
    }
}

// ---------- k/q/v: grid 1536; 16 out-ch slices; streaming input ----------
__global__ __launch_bounds__(256) void k_kqv(
    const float* __restrict__ t1,
    const float* __restrict__ Wk, const float* __restrict__ bk,
    const float* __restrict__ Wq, const float* __restrict__ bq,
    const float* __restrict__ Wv, const float* __restrict__ bv,
    const float* __restrict__ fbn,
    float* __restrict__ kout, float* __restrict__ qout, float* __restrict__ vout)
{
    __shared__ float Wt[CH*16];
    __shared__ float4 fL[32];
    __shared__ float4 bias4[4];
    const int tid = threadIdx.x;
    const int m = blockIdx.x / 512;
    const int rem = blockIdx.x & 511;
    const int rb = rem >> 2;
    const int c0 = (rem & 3)*16;
    const float* W  = (m==0) ? Wk : (m==1 ? Wq : Wv);
    const float* bs = (m==0) ? bk : (m==1 ? bq : bv);
    float* o        = (m==0) ? kout : (m==1 ? qout : vout);
    #pragma unroll
    for (int ch=0; ch<4; ++ch){
        const int idx = ch*256 + tid;
        Wt[idx] = W[(size_t)(c0 + (idx & 15))*CH + (idx >> 4)];
    }
    if (tid < 32) fL[tid] = ((const float4*)fbn)[tid];
    if (tid < 4)  bias4[tid] = ((const float4*)(bs + c0))[tid];
    __syncthreads();

    const int row = rb*256 + tid;
    const float4* iv = (const float4*)(t1 + (size_t)row*CH);
    const float4* Wt4 = (const float4*)Wt;
    float4 a0 = bias4[0], a1 = bias4[1], a2 = bias4[2], a3 = bias4[3];
    #pragma unroll
    for (int j=0;j<16;++j){
        float4 x4 = iv[j];
        float4 s4 = fL[j], h4 = fL[16+j];
        x4.x = frelu(x4.x*s4.x+h4.x); x4.y = frelu(x4.y*s4.y+h4.y);
        x4.z = frelu(x4.z*s4.z+h4.z); x4.w = frelu(x4.w*s4.w+h4.w);
        #define KSTEP(comp, xv) { \
            float4 wq0 = Wt4[(4*j+comp)*4+0], wq1 = Wt4[(4*j+comp)*4+1]; \
            float4 wq2 = Wt4[(4*j+comp)*4+2], wq3 = Wt4[(4*j+comp)*4+3]; \
            a0.x += (xv)*wq0.x; a0.y += (xv)*wq0.y; a0.z += (xv)*wq0.z; a0.w += (xv)*wq0.w; \
            a1.x += (xv)*wq1.x; a1.y += (xv)*wq1.y; a1.z += (xv)*wq1.z; a1.w += (xv)*wq1.w; \
            a2.x += (xv)*wq2.x; a2.y += (xv)*wq2.y; a2.z += (xv)*wq2.z; a2.w += (xv)*wq2.w; \
            a3.x += (xv)*wq3.x; a3.y += (xv)*wq3.y; a3.z += (xv)*wq3.z; a3.w += (xv)*wq3.w; }
        KSTEP(0, x4.x) KSTEP(1, x4.y) KSTEP(2, x4.z) KSTEP(3, x4.w)
        #undef KSTEP
    }
    float4* ov = (float4*)(o + (size_t)row*CH + c0);
    ov[0]=a0; ov[1]=a1; ov[2]=a2; ov[3]=a3;
}

// ---------- w_bn1 stats over apre = k[src]-q[dst]+delta (lane = channel) ----------
__global__ __launch_bounds__(256) void k_edge1(
    const int* __restrict__ esrc, const float4* __restrict__ u4,
    const float* __restrict__ kbuf, const float* __restrict__ qbuf,
    const float* __restrict__ fP,
    const float* __restrict__ p2w, const float* __restrict__ p2b,
    float* __restrict__ gstat)
{
    __shared__ float red[4][128];
    const int tid = threadIdx.x;
    const int c = tid & 63, wv = tid >> 6;
    const float scp0=fP[0], scp1=fP[1], scp2=fP[2];
    const float shp0=fP[64], shp1=fP[65], shp2=fP[66];
    const float w0 = p2w[c*3+0], w1 = p2w[c*3+1], w2 = p2w[c*3+2], bc = p2b[c];

    const int gw = blockIdx.x*4 + wv;      // 16384 waves
    const int chunk = NE/16384;            // 32 edges/wave
    const int e0 = gw*chunk;
    float s=0.f, q=0.f;
    #pragma unroll 4
    for (int e = e0; e < e0+chunk; ++e) {
        int sj = esrc[e]; int d = e >> 4;
        float4 uu = u4[e];
        float r0 = frelu(uu.x*scp0+shp0);
        float r1 = frelu(uu.y*scp1+shp1);
        float r2 = frelu(uu.z*scp2+shp2);
        float a = kbuf[(size_t)sj*CH+c] - qbuf[(size_t)d*CH+c]
                + (r0*w0 + r1*w1 + r2*w2 + bc);
        s += a; q += a*a;
    }
    red[wv][c] = s; red[wv][64+c] = q;
    __syncthreads();
    if (tid < 128) {
        float t = red[0][tid]+red[1][tid]+red[2][tid]+red[3][tid];
        atomicAdd(&gstat[(blockIdx.x & (NREP-1))*128 + tid], t);
    }
}

// ---------- a2: 16 lanes per edge, coalesced k-row gather, butterfly reduce ----------
// grid NE/16 = 32768 blocks
__global__ __launch_bounds__(256) void k_edge2(
    const int* __restrict__ esrc, const float4* __restrict__ u4,
    const float* __restrict__ kbuf, const float* __restrict__ qbuf,
    const float* __restrict__ fP,
    const float* __restrict__ p2w, const float* __restrict__ p2b,
    const float* __restrict__ fW1,
    const float* __restrict__ w1w, const float* __restrict__ w1bias,
    float* __restrict__ a2out, float* __restrict__ gstat)
{
    __shared__ float4 w1L[128];     // w1L[jout*16 + t] = w1w[jout*64 + 4t .. +3]
    __shared__ float red[4][16];
    const int tid = threadIdx.x;
    if (tid < 128) w1L[tid] = ((const float4*)w1w)[tid];
    __syncthreads();

    const int t = tid & 15;
    const int e = blockIdx.x*16 + (tid >> 4);
    const int sj = esrc[e]; const int d = e >> 4;
    const int c0 = 4*t;
    const float scp0=fP[0], scp1=fP[1], scp2=fP[2];
    const float shp0=fP[64], shp1=fP[65], shp2=fP[66];
    float4 uu = u4[e];
    const float r0 = frelu(uu.x*scp0+shp0);
    const float r1 = frelu(uu.y*scp1+shp1);
    const float r2 = frelu(uu.z*scp2+shp2);
    float4 k4 = ((const float4*)(kbuf + (size_t)sj*CH))[t];
    float4 q4 = ((const float4*)(qbuf + (size_t)d*CH))[t];
    float4 pb4 = ((const float4*)p2b)[t];
    float4 sc4 = ((const float4*)fW1)[t];
    float4 sh4 = ((const float4*)(fW1+64))[t];
    float pw[12];
    #pragma unroll
    for (int k2=0;k2<12;++k2) pw[k2] = p2w[c0*3+k2];
    const float b0 = frelu((k4.x - q4.x + r0*pw[0]+r1*pw[1]+r2*pw[2] +pb4.x)*sc4.x+sh4.x);
    const float b1 = frelu((k4.y - q4.y + r0*pw[3]+r1*pw[4]+r2*pw[5] +pb4.y)*sc4.y+sh4.y);
    const float b2 = frelu((k4.z - q4.z + r0*pw[6]+r1*pw[7]+r2*pw[8] +pb4.z)*sc4.z+sh4.z);
    const float b3 = frelu((k4.w - q4.w + r0*pw[9]+r1*pw[10]+r2*pw[11]+pb4.w)*sc4.w+sh4.w);
    float p[8];
    #pragma unroll
    for (int j=0;j<8;++j){
        float4 w4 = w1L[j*16 + t];
        p[j] = b0*w4.x + b1*w4.y + b2*w4.z + b3*w4.w;
    }
    // butterfly over the 16-lane edge group
    #pragma unroll
    for (int msk=8;msk>=1;msk>>=1){
        #pragma unroll
        for (int j=0;j<8;++j) p[j] += __shfl_xor(p[j], msk);
    }
    float a2f[8], sq[8];
    #pragma unroll
    for (int j=0;j<8;++j){ a2f[j] = p[j] + w1bias[j]; sq[j] = a2f[j]*a2f[j]; }
    if (t < 2) {
        float4 w = (t==0) ? make_float4(a2f[0],a2f[1],a2f[2],a2f[3])
                          : make_float4(a2f[4],a2f[5],a2f[6],a2f[7]);
        ((float4*)a2out)[(size_t)e*2 + t] = w;
    }
    // cross-group (wave) reduce: groups are lanes {0-15,16-31,32-47,48-63}
    #pragma unroll
    for (int msk=32;msk>=16;msk>>=1){
        #pragma unroll
        for (int j=0;j<8;++j){ a2f[j]+=__shfl_xor(a2f[j],msk); sq[j]+=__shfl_xor(sq[j],msk); }
    }
    const int wv = tid>>6;
    if ((tid&63)==0){
        #pragma unroll
        for (int j=0;j<8;++j){ red[wv][j]=a2f[j]; red[wv][8+j]=sq[j]; }
    }
    __syncthreads();
    if (tid < 16) {
        float tt = red[0][tid]+red[1][tid]+red[2][tid]+red[3][tid];
        int dstc = (tid<8) ? tid : (64 + tid - 8);
        atomicAdd(&gstat[(blockIdx.x & (NREP-1))*128 + dstc], tt);
    }
}

// ---------- bn_w2 + w2 matmul + softmax (A), channel-owner aggregation (B) + bn2 stats ----------
__global__ __launch_bounds__(256) void k_attn(
    const int* __restrict__ esrc, const float4* __restrict__ u4,
    const float* __restrict__ vbuf, const float* __restrict__ a2buf,
    const float* __restrict__ fP,
    const float* __restrict__ p2w, const float* __restrict__ p2b,
    const float* __restrict__ fW2,
    const float* __restrict__ w2w, const float* __restrict__ w2bias,
    float* __restrict__ outbuf, float* __restrict__ gstat)
{
    __shared__ float red[4][128];
    __shared__ float att[256][8];
    __shared__ float rrL[256][4];
    __shared__ int   sjL[256];
    const int tid = threadIdx.x;
    const float scp0=fP[0], scp1=fP[1], scp2=fP[2];
    const float shp0=fP[64], shp1=fP[65], shp2=fP[66];

    const int t = tid & 15;
    const int i = blockIdx.x*16 + (tid>>4);
    const int e = i*KNN + t;
    const int sj = esrc[e];
    sjL[tid] = sj;
    {
        float4 uu = u4[e];
        rrL[tid][0] = frelu(uu.x*scp0+shp0);
        rrL[tid][1] = frelu(uu.y*scp1+shp1);
        rrL[tid][2] = frelu(uu.z*scp2+shp2);
    }
    // ---- phase A ----
    {
        const float4* a2v = (const float4*)a2buf;
        float4 aA = a2v[(size_t)e*2], aB = a2v[(size_t)e*2+1];
        float bb[8];
        bb[0]=frelu(aA.x*fW2[0]+fW2[64]); bb[1]=frelu(aA.y*fW2[1]+fW2[65]);
        bb[2]=frelu(aA.z*fW2[2]+fW2[66]); bb[3]=frelu(aA.w*fW2[3]+fW2[67]);
        bb[4]=frelu(aB.x*fW2[4]+fW2[68]); bb[5]=frelu(aB.y*fW2[5]+fW2[69]);
        bb[6]=frelu(aB.z*fW2[6]+fW2[70]); bb[7]=frelu(aB.w*fW2[7]+fW2[71]);
        float at[8];
        #pragma unroll
        for (int s=0;s<8;++s){
            float a3 = w2bias[s];
            #pragma unroll
            for (int u=0;u<8;++u) a3 += bb[u]*w2w[s*8+u];
            float m = a3;
            #pragma unroll
            for (int msk=8;msk>=1;msk>>=1) m = fmaxf(m, __shfl_xor(m,msk));
            float p = __expf(a3-m);
            float ssm = p;
            #pragma unroll
            for (int msk=8;msk>=1;msk>>=1) ssm += __shfl_xor(ssm,msk);
            at[s] = p/ssm;
        }
        ((float4*)att[tid])[0] = make_float4(at[0],at[1],at[2],at[3]);
        ((float4*)att[tid])[1] = make_float4(at[4],at[5],at[6],at[7]);
    }
    __syncthreads();
    // ---- phase B: thread owns channels 4t..4t+3 of point i ----
    const int base = (tid>>4)*16;
    const int c0 = 4*t;
    const int ho = (t&1);
    float pw[12], pbv[4];
    #pragma unroll
    for (int k2=0;k2<12;++k2) pw[k2] = p2w[c0*3+k2];
    #pragma unroll
    for (int k2=0;k2<4;++k2)  pbv[k2] = p2b[c0+k2];
    float4 res = make_float4(0,0,0,0);
    #pragma unroll 4
    for (int n=0; n<16; ++n){
        const int sjn = sjL[base+n];
        float4 v4 = ((const float4*)(vbuf + (size_t)sjn*CH))[t];
        const float rr0 = rrL[base+n][0], rr1 = rrL[base+n][1], rr2 = rrL[base+n][2];
        float4 a4 = ((const float4*)att[base+n])[ho];
        res.x += a4.x*(v4.x + rr0*pw[0]+rr1*pw[1]+rr2*pw[2]+pbv[0]);
        res.y += a4.y*(v4.y + rr0*pw[3]+rr1*pw[4]+rr2*pw[5]+pbv[1]);
        res.z += a4.z*(v4.z + rr0*pw[6]+rr1*pw[7]+rr2*pw[8]+pbv[2]);
        res.w += a4.w*(v4.w + rr0*pw[9]+rr1*pw[10]+rr2*pw[11]+pbv[3]);
    }
    ((float4*)outbuf)[(size_t)i*16 + t] = res;

    // fused bn2 stats
    float4 sq = make_float4(res.x*res.x, res.y*res.y, res.z*res.z, res.w*res.w);
    #pragma unroll
    for (int msk=32;msk>=16;msk>>=1){
        res.x+=__shfl_xor(res.x,msk); res.y+=__shfl_xor(res.y,msk);
        res.z+=__shfl_xor(res.z,msk); res.w+=__shfl_xor(res.w,msk);
        sq.x+=__shfl_xor(sq.x,msk);  sq.y+=__shfl_xor(sq.y,msk);
        sq.z+=__shfl_xor(sq.z,msk);  sq.w+=__shfl_xor(sq.w,msk);
    }
    const int wv = tid>>6;
    if ((tid&63) < 16){
        red[wv][t*4+0]=res.x; red[wv][t*4+1]=res.y; red[wv][t*4+2]=res.z; red[wv][t*4+3]=res.w;
        red[wv][64+t*4+0]=sq.x; red[wv][64+t*4+1]=sq.y; red[wv][64+t*4+2]=sq.z; red[wv][64+t*4+3]=sq.w;
    }
    __syncthreads();
    if (tid < 128) {
        float tt = red[0][tid]+red[1][tid]+red[2][tid]+red[3][tid];
        atomicAdd(&gstat[(blockIdx.x & (NREP-1))*128 + tid], tt);
    }
}

// ---------- final = relu(bn3(h3) + x_skip) ----------
__global__ __launch_bounds__(256) void k_final(
    const float* __restrict__ h3, const float* __restrict__ x,
    const float* __restrict__ fbn, float* __restrict__ out)
{
    const int tid = threadIdx.x;
    const int gi = blockIdx.x*256 + tid;
    const int c0 = (gi & 15)*4;
    float sc0=fbn[c0],sc1=fbn[c0+1],sc2=fbn[c0+2],sc3=fbn[c0+3];
    float sh0=fbn[64+c0],sh1=fbn[64+c0+1],sh2=fbn[64+c0+2],sh3=fbn[64+c0+3];
    float4 h = ((const float4*)h3)[gi];
    float4 xv = ((const float4*)x)[gi];
    float4 o;
    o.x = fmaxf(h.x*sc0+sh0+xv.x, 0.f);
    o.y = fmaxf(h.y*sc1+sh1+xv.y, 0.f);
    o.z = fmaxf(h.z*sc2+sh2+xv.z, 0.f);
    o.w = fmaxf(h.w*sc3+sh3+xv.w, 0.f);
    ((float4*)out)[gi] = o;
}

extern "C" void kernel_launch(void* const* d_in, const int* in_sizes, int n_in,
                              void* d_out, int out_size, void* d_ws, size_t ws_size,
                              hipStream_t stream) {
    (void)in_sizes; (void)n_in; (void)out_size; (void)ws_size;
    const float* pos   = (const float*)d_in[0];
    const float* x     = (const float*)d_in[1];
    const float* W1    = (const float*)d_in[2];
    const float* Wk    = (const float*)d_in[3];
    const float* bk    = (const float*)d_in[4];
    const float* Wq    = (const float*)d_in[5];
    const float* bq    = (const float*)d_in[6];
    const float* Wv    = (const float*)d_in[7];
    const float* bv    = (const float*)d_in[8];
    const float* p1w   = (const float*)d_in[9];
    const float* p1b   = (const float*)d_in[10];
    const float* pg    = (const float*)d_in[11];
    const float* pb    = (const float*)d_in[12];
    const float* p2w   = (const float*)d_in[13];
    const float* p2b   = (const float*)d_in[14];
    const float* w1g   = (const float*)d_in[15];
    const float* w1bb  = (const float*)d_in[16];
    const float* w1w   = (const float*)d_in[17];
    const float* w1bias= (const float*)d_in[18];
    const float* w2g   = (const float*)d_in[19];
    const float* w2bb  = (const float*)d_in[20];
    const float* w2w   = (const float*)d_in[21];
    const float* w2bias= (const float*)d_in[22];
    const float* W3    = (const float*)d_in[23];
    const float* bn1g  = (const float*)d_in[24];
    const float* bn1b  = (const float*)d_in[25];
    const float* bn2g  = (const float*)d_in[26];
    const float* bn2b  = (const float*)d_in[27];
    const float* bn3g  = (const float*)d_in[28];
    const float* bn3b  = (const float*)d_in[29];
    const int*   ei    = (const int*)d_in[30];
    float* ws  = (float*)d_ws;
    float* out = (float*)d_out;

    hipMemsetAsync(ws, 0, STATS_FLOATS*sizeof(float), stream);

    // u precompute + p-bn stats
    k_pstats_u<<<2048, 256, 0, stream>>>(pos, ei, p1w, p1b,
        (float4*)(ws+OFF_U), ws+G_P);
    // t1 = x @ W1^T + bn1 stats
    k_gemm64<<<512, 256, 0, stream>>>(x, W1, ws+OFF_T1, nullptr, 0, ws+G_BN1);
    // finalize P and BN1
    k_fin<<<2, 128, 0, stream>>>(ws+G_P, 1.f/NE, pg, pb, ws+F_P, 3,
                                 ws+G_BN1, 1.f/NPTS, bn1g, bn1b, ws+F_BN1, 64);
    // k,q,v
    k_kqv<<<1536, 256, 0, stream>>>(ws+OFF_T1, Wk, bk, Wq, bq, Wv, bv,
        ws+F_BN1, ws+OFF_K, ws+OFF_Q, ws+OFF_V);
    // w_bn1 stats
    k_edge1<<<4096, 256, 0, stream>>>(ei, (const float4*)(ws+OFF_U),
        ws+OFF_K, ws+OFF_Q, ws+F_P, p2w, p2b, ws+G_W1);
    // finalize W1
    k_fin<<<1, 128, 0, stream>>>(ws+G_W1, 1.f/NE, w1g, w1bb, ws+F_W1, 64,
                                 nullptr, 0.f, nullptr, nullptr, nullptr, 0);
    // a2 + w_bn2 stats
    k_edge2<<<32768, 256, 0, stream>>>(ei, (const float4*)(ws+OFF_U),
        ws+OFF_K, ws+OFF_Q, ws+F_P, p2w, p2b,
        ws+F_W1, w1w, w1bias, ws+OFF_A2, ws+G_W2);
    // finalize W2
    k_fin<<<1, 128, 0, stream>>>(ws+G_W2, 1.f/NE, w2g, w2bb, ws+F_W2, 8,
                                 nullptr, 0.f, nullptr, nullptr, nullptr, 0);
    // softmax + aggregate + bn2 stats
    k_attn<<<2048, 256, 0, stream>>>(ei, (const float4*)(ws+OFF_U),
        ws+OFF_V, ws+OFF_A2, ws+F_P, p2w, p2b,
        ws+F_W2, w2w, w2bias, ws+OFF_OUT, ws+G_BN2);
    // finalize BN2
    k_fin<<<1, 128, 0, stream>>>(ws+G_BN2, 1.f/NPTS, bn2g, bn2b, ws+F_BN2, 64,
                                 nullptr, 0.f, nullptr, nullptr, nullptr, 0);
    // h3 = relu(bn2(out)) @ W3^T + bn3 stats
    k_gemm64<<<512, 256, 0, stream>>>(ws+OFF_OUT, W3, ws+OFF_H3,
        ws+F_BN2, 1, ws+G_BN3);
    // finalize BN3
    k_fin<<<1, 128, 0, stream>>>(ws+G_BN3, 1.f/NPTS, bn3g, bn3b, ws+F_BN3, 64,
                                 nullptr, 0.f, nullptr, nullptr, nullptr, 0);
    // final
    k_final<<<2048, 256, 0, stream>>>(ws+OFF_H3, x, ws+F_BN3, out);
}

// Round 8
// 371.239 us; speedup vs baseline: 1.5774x; 1.5774x over previous
//
#include <hip/hip_runtime.h>

#define NPTS 32768
#define CH 64
#define KNN 16
#define NE (NPTS*KNN)
#define EPS 1e-5f
#define NREP 32

// raw stats groups: NREP replicas x 128 floats; sums at [c], sumsq at [64+c]
#define G_P   0
#define G_BN1 (1*NREP*128)
#define G_W1  (2*NREP*128)
#define G_W2  (3*NREP*128)
#define G_BN2 (4*NREP*128)
#define G_BN3 (5*NREP*128)
#define STATS_FLOATS (6*NREP*128)

// finalized scale/shift: 128 floats each: [sc 0..63][sh 64..127]
#define F_P   (STATS_FLOATS + 0*128)
#define F_BN1 (STATS_FLOATS + 1*128)
#define F_W1  (STATS_FLOATS + 2*128)
#define F_W2  (STATS_FLOATS + 3*128)
#define F_BN2 (STATS_FLOATS + 4*128)
#define F_BN3 (STATS_FLOATS + 5*128)

#define OFF_T1  (STATS_FLOATS + 1024)
#define SZ_NC   (NPTS*CH)
#define OFF_K   (OFF_T1 + SZ_NC)
#define OFF_Q   (OFF_K + SZ_NC)
#define OFF_V   (OFF_Q + SZ_NC)
#define OFF_A2  (OFF_V + SZ_NC)
#define OFF_OUT (OFF_A2 + NE*8)
#define OFF_U   (OFF_OUT + SZ_NC)   /* NE*4 floats; shared with H3 (dead by then) */
#define OFF_H3  OFF_U

__device__ __forceinline__ float frelu(float x){ return fmaxf(x, 0.f); }

// ---------- finalize up to two stats groups -> [sc|sh] ----------
__global__ __launch_bounds__(128) void k_fin(
    const float* __restrict__ gA, float invA, const float* __restrict__ gmA,
    const float* __restrict__ btA, float* __restrict__ outA, int nchA,
    const float* __restrict__ gB, float invB, const float* __restrict__ gmB,
    const float* __restrict__ btB, float* __restrict__ outB, int nchB)
{
    __shared__ float s_tmp[128];
    const int tid = threadIdx.x;
    const float* g; float inv; const float* gm; const float* bt; float* o; int nch;
    if (blockIdx.x == 0) { g=gA; inv=invA; gm=gmA; bt=btA; o=outA; nch=nchA; }
    else { if (!outB) return; g=gB; inv=invB; gm=gmB; bt=btB; o=outB; nch=nchB; }
    float t = 0.f;
    #pragma unroll
    for (int r=0;r<NREP;++r) t += g[r*128+tid];
    s_tmp[tid] = t;
    __syncthreads();
    if (tid < 64) {
        if (tid < nch) {
            float m = s_tmp[tid]*inv;
            float v = s_tmp[64+tid]*inv - m*m;
            float s = gm[tid]*rsqrtf(v+EPS);
            o[tid] = s; o[64+tid] = bt[tid] - m*s;
        } else { o[tid]=0.f; o[64+tid]=0.f; }
    }
}

// ---------- u = rel @ p1_w^T + p1_b per edge (stored), plus p-bn stats ----------
__global__ __launch_bounds__(256) void k_pstats_u(
    const float* __restrict__ pos, const int* __restrict__ esrc,
    const float* __restrict__ p1w, const float* __restrict__ p1b,
    float4* __restrict__ u4, float* __restrict__ gstat)
{
    __shared__ float red[4][6];
    const int tid = threadIdx.x;
    const float w0=p1w[0],w1=p1w[1],w2=p1w[2],w3=p1w[3],w4=p1w[4],w5=p1w[5],w6=p1w[6],w7=p1w[7],w8=p1w[8];
    const float b0=p1b[0],b1=p1b[1],b2=p1b[2];
    const int e = blockIdx.x*256 + tid;
    const int sj = esrc[e]; const int d = e >> 4;
    float ax = pos[3*sj]-pos[3*d], ay = pos[3*sj+1]-pos[3*d+1], az = pos[3*sj+2]-pos[3*d+2];
    float u0 = w0*ax+w1*ay+w2*az+b0;
    float u1 = w3*ax+w4*ay+w5*az+b1;
    float u2 = w6*ax+w7*ay+w8*az+b2;
    u4[e] = make_float4(u0,u1,u2,0.f);
    float s0=u0,s1=u1,s2=u2,q0=u0*u0,q1=u1*u1,q2=u2*u2;
    #pragma unroll
    for (int m=32;m>=1;m>>=1){
        s0+=__shfl_xor(s0,m); s1+=__shfl_xor(s1,m); s2+=__shfl_xor(s2,m);
        q0+=__shfl_xor(q0,m); q1+=__shfl_xor(q1,m); q2+=__shfl_xor(q2,m);
    }
    const int wv = tid>>6;
    if ((tid&63)==0){ red[wv][0]=s0; red[wv][1]=s1; red[wv][2]=s2;
                      red[wv][3]=q0; red[wv][4]=q1; red[wv][5]=q2; }
    __syncthreads();
    float* g = gstat + (blockIdx.x & (NREP-1))*128;
    if (tid < 3)      atomicAdd(&g[tid],        red[0][tid]+red[1][tid]+red[2][tid]+red[3][tid]);
    else if (tid < 6) atomicAdd(&g[64+(tid-3)], red[0][tid]+red[1][tid]+red[2][tid]+red[3][tid]);
}

// ---------- [N,64]@W^T; 2 rows/thread x 16 out-ch; bounded inner loop ----------
// grid 256: rb = bid>>2 (64 rowblocks of 512), slice = bid&3
__global__ __launch_bounds__(256) void k_gemm64(
    const float* __restrict__ in, const float* __restrict__ W,
    float* __restrict__ out,
    const float* __restrict__ fbn, int applyBn,
    float* __restrict__ gstat)
{
    __shared__ float Wt[CH*16];     // Wt[i*16 + r] = W[c0+r][i]
    __shared__ float4 fL[32];
    __shared__ float red[4][32];
    const int tid = threadIdx.x;
    const int wv = tid >> 6;
    const int rb = blockIdx.x >> 2;
    const int c0 = (blockIdx.x & 3)*16;
    #pragma unroll
    for (int ch=0; ch<4; ++ch){
        const int idx = ch*256 + tid;
        Wt[idx] = W[(size_t)(c0 + (idx & 15))*CH + (idx >> 4)];
    }
    if (applyBn && tid < 32) fL[tid] = ((const float4*)fbn)[tid];
    __syncthreads();

    const int row0 = rb*512 + tid;
    const float4* iv0 = (const float4*)(in + (size_t)row0*CH);
    const float4* iv1 = (const float4*)(in + (size_t)(row0+256)*CH);
    const float4* Wt4 = (const float4*)Wt;
    float4 A0=make_float4(0,0,0,0),A1=A0,A2=A0,A3=A0;
    float4 B0=A0,B1=A0,B2=A0,B3=A0;
    #pragma unroll 1
    for (int jj=0;jj<16;++jj){
        float4 x0 = iv0[jj], x1 = iv1[jj];
        if (applyBn){
            float4 s4 = fL[jj], h4 = fL[16+jj];
            x0.x=frelu(x0.x*s4.x+h4.x); x0.y=frelu(x0.y*s4.y+h4.y);
            x0.z=frelu(x0.z*s4.z+h4.z); x0.w=frelu(x0.w*s4.w+h4.w);
            x1.x=frelu(x1.x*s4.x+h4.x); x1.y=frelu(x1.y*s4.y+h4.y);
            x1.z=frelu(x1.z*s4.z+h4.z); x1.w=frelu(x1.w*s4.w+h4.w);
        }
        const float4* wb = &Wt4[jj*16];
        #define MSTEP(xa, xb, base) { \
            float4 w_0=wb[(base)+0], w_1=wb[(base)+1], w_2=wb[(base)+2], w_3=wb[(base)+3]; \
            A0.x+=(xa)*w_0.x; A0.y+=(xa)*w_0.y; A0.z+=(xa)*w_0.z; A0.w+=(xa)*w_0.w; \
            A1.x+=(xa)*w_1.x; A1.y+=(xa)*w_1.y; A1.z+=(xa)*w_1.z; A1.w+=(xa)*w_1.w; \
            A2.x+=(xa)*w_2.x; A2.y+=(xa)*w_2.y; A2.z+=(xa)*w_2.z; A2.w+=(xa)*w_2.w; \
            A3.x+=(xa)*w_3.x; A3.y+=(xa)*w_3.y; A3.z+=(xa)*w_3.z; A3.w+=(xa)*w_3.w; \
            B0.x+=(xb)*w_0.x; B0.y+=(xb)*w_0.y; B0.z+=(xb)*w_0.z; B0.w+=(xb)*w_0.w; \
            B1.x+=(xb)*w_1.x; B1.y+=(xb)*w_1.y; B1.z+=(xb)*w_1.z; B1.w+=(xb)*w_1.w; \
            B2.x+=(xb)*w_2.x; B2.y+=(xb)*w_2.y; B2.z+=(xb)*w_2.z; B2.w+=(xb)*w_2.w; \
            B3.x+=(xb)*w_3.x; B3.y+=(xb)*w_3.y; B3.z+=(xb)*w_3.z; B3.w+=(xb)*w_3.w; }
        MSTEP(x0.x, x1.x, 0) MSTEP(x0.y, x1.y, 4) MSTEP(x0.z, x1.z, 8) MSTEP(x0.w, x1.w, 12)
        #undef MSTEP
    }
    float4* ov0 = (float4*)(out + (size_t)row0*CH + c0);
    float4* ov1 = (float4*)(out + (size_t)(row0+256)*CH + c0);
    ov0[0]=A0; ov0[1]=A1; ov0[2]=A2; ov0[3]=A3;
    ov1[0]=B0; ov1[1]=B1; ov1[2]=B2; ov1[3]=B3;
    #define STATQ(q, A, B) { \
        float4 s = make_float4(A.x+B.x, A.y+B.y, A.z+B.z, A.w+B.w); \
        float4 sq = make_float4(A.x*A.x+B.x*B.x, A.y*A.y+B.y*B.y, A.z*A.z+B.z*B.z, A.w*A.w+B.w*B.w); \
        _Pragma("unroll") \
        for (int m=32;m>=1;m>>=1){ \
            s.x+=__shfl_xor(s.x,m); s.y+=__shfl_xor(s.y,m); \
            s.z+=__shfl_xor(s.z,m); s.w+=__shfl_xor(s.w,m); \
            sq.x+=__shfl_xor(sq.x,m); sq.y+=__shfl_xor(sq.y,m); \
            sq.z+=__shfl_xor(sq.z,m); sq.w+=__shfl_xor(sq.w,m); } \
        if ((tid&63)==0){ \
            red[wv][q*4+0]=s.x; red[wv][q*4+1]=s.y; red[wv][q*4+2]=s.z; red[wv][q*4+3]=s.w; \
            red[wv][16+q*4+0]=sq.x; red[wv][16+q*4+1]=sq.y; red[wv][16+q*4+2]=sq.z; red[wv][16+q*4+3]=sq.w; } }
    STATQ(0, A0, B0) STATQ(1, A1, B1) STATQ(2, A2, B2) STATQ(3, A3, B3)
    #undef STATQ
    __syncthreads();
    if (tid < 32) {
        float t = red[0][tid]+red[1][tid]+red[2][tid]+red[3][tid];
        int dstc = (tid<16) ? (c0+tid) : (64 + c0 + (tid-16));
        atomicAdd(&gstat[(blockIdx.x & (NREP-1))*128 + dstc], t);
    }
}

// ---------- k/q/v: grid 768; m=bid/256; 2 rows/thread x 16 out-ch ----------
__global__ __launch_bounds__(256) void k_kqv(
    const float* __restrict__ t1,
    const float* __restrict__ Wk, const float* __restrict__ bk,
    const float* __restrict__ Wq, const float* __restrict__ bq,
    const float* __restrict__ Wv, const float* __restrict__ bv,
    const float* __restrict__ fbn,
    float* __restrict__ kout, float* __restrict__ qout, float* __restrict__ vout)
{
    __shared__ float Wt[CH*16];
    __shared__ float4 fL[32];
    __shared__ float4 bias4[4];
    const int tid = threadIdx.x;
    const int m = blockIdx.x / 256;
    const int rem = blockIdx.x & 255;
    const int rb = rem >> 2;
    const int c0 = (rem & 3)*16;
    const float* W  = (m==0) ? Wk : (m==1 ? Wq : Wv);
    const float* bs = (m==0) ? bk : (m==1 ? bq : bv);
    float* o        = (m==0) ? kout : (m==1 ? qout : vout);
    #pragma unroll
    for (int ch=0; ch<4; ++ch){
        const int idx = ch*256 + tid;
        Wt[idx] = W[(size_t)(c0 + (idx & 15))*CH + (idx >> 4)];
    }
    if (tid < 32) fL[tid] = ((const float4*)fbn)[tid];
    if (tid < 4)  bias4[tid] = ((const float4*)(bs + c0))[tid];
    __syncthreads();

    const int row0 = rb*512 + tid;
    const float4* iv0 = (const float4*)(t1 + (size_t)row0*CH);
    const float4* iv1 = (const float4*)(t1 + (size_t)(row0+256)*CH);
    const float4* Wt4 = (const float4*)Wt;
    float4 A0=bias4[0],A1=bias4[1],A2=bias4[2],A3=bias4[3];
    float4 B0=bias4[0],B1=bias4[1],B2=bias4[2],B3=bias4[3];
    #pragma unroll 1
    for (int jj=0;jj<16;++jj){
        float4 x0 = iv0[jj], x1 = iv1[jj];
        float4 s4 = fL[jj], h4 = fL[16+jj];
        x0.x=frelu(x0.x*s4.x+h4.x); x0.y=frelu(x0.y*s4.y+h4.y);
        x0.z=frelu(x0.z*s4.z+h4.z); x0.w=frelu(x0.w*s4.w+h4.w);
        x1.x=frelu(x1.x*s4.x+h4.x); x1.y=frelu(x1.y*s4.y+h4.y);
        x1.z=frelu(x1.z*s4.z+h4.z); x1.w=frelu(x1.w*s4.w+h4.w);
        const float4* wb = &Wt4[jj*16];
        #define MSTEP(xa, xb, base) { \
            float4 w_0=wb[(base)+0], w_1=wb[(base)+1], w_2=wb[(base)+2], w_3=wb[(base)+3]; \
            A0.x+=(xa)*w_0.x; A0.y+=(xa)*w_0.y; A0.z+=(xa)*w_0.z; A0.w+=(xa)*w_0.w; \
            A1.x+=(xa)*w_1.x; A1.y+=(xa)*w_1.y; A1.z+=(xa)*w_1.z; A1.w+=(xa)*w_1.w; \
            A2.x+=(xa)*w_2.x; A2.y+=(xa)*w_2.y; A2.z+=(xa)*w_2.z; A2.w+=(xa)*w_2.w; \
            A3.x+=(xa)*w_3.x; A3.y+=(xa)*w_3.y; A3.z+=(xa)*w_3.z; A3.w+=(xa)*w_3.w; \
            B0.x+=(xb)*w_0.x; B0.y+=(xb)*w_0.y; B0.z+=(xb)*w_0.z; B0.w+=(xb)*w_0.w; \
            B1.x+=(xb)*w_1.x; B1.y+=(xb)*w_1.y; B1.z+=(xb)*w_1.z; B1.w+=(xb)*w_1.w; \
            B2.x+=(xb)*w_2.x; B2.y+=(xb)*w_2.y; B2.z+=(xb)*w_2.z; B2.w+=(xb)*w_2.w; \
            B3.x+=(xb)*w_3.x; B3.y+=(xb)*w_3.y; B3.z+=(xb)*w_3.z; B3.w+=(xb)*w_3.w; }
        MSTEP(x0.x, x1.x, 0) MSTEP(x0.y, x1.y, 4) MSTEP(x0.z, x1.z, 8) MSTEP(x0.w, x1.w, 12)
        #undef MSTEP
    }
    float4* ov0 = (float4*)(o + (size_t)row0*CH + c0);
    float4* ov1 = (float4*)(o + (size_t)(row0+256)*CH + c0);
    ov0[0]=A0; ov0[1]=A1; ov0[2]=A2; ov0[3]=A3;
    ov1[0]=B0; ov1[1]=B1; ov1[2]=B2; ov1[3]=B3;
}

// ---------- w_bn1 stats over apre = k[src]-q[dst]+delta (lane = channel) ----------
__global__ __launch_bounds__(256) void k_edge1(
    const int* __restrict__ esrc, const float4* __restrict__ u4,
    const float* __restrict__ kbuf, const float* __restrict__ qbuf,
    const float* __restrict__ fP,
    const float* __restrict__ p2w, const float* __restrict__ p2b,
    float* __restrict__ gstat)
{
    __shared__ float red[4][128];
    const int tid = threadIdx.x;
    const int c = tid & 63, wv = tid >> 6;
    const float scp0=fP[0], scp1=fP[1], scp2=fP[2];
    const float shp0=fP[64], shp1=fP[65], shp2=fP[66];
    const float w0 = p2w[c*3+0], w1 = p2w[c*3+1], w2 = p2w[c*3+2], bc = p2b[c];

    const int gw = blockIdx.x*4 + wv;      // 32768 waves
    const int chunk = NE/32768;            // 16 edges/wave (one dst group)
    const int e0 = gw*chunk;
    float s=0.f, q=0.f;
    #pragma unroll 4
    for (int e = e0; e < e0+chunk; ++e) {
        int sj = esrc[e]; int d = e >> 4;
        float4 uu = u4[e];
        float r0 = frelu(uu.x*scp0+shp0);
        float r1 = frelu(uu.y*scp1+shp1);
        float r2 = frelu(uu.z*scp2+shp2);
        float a = kbuf[(size_t)sj*CH+c] - qbuf[(size_t)d*CH+c]
                + (r0*w0 + r1*w1 + r2*w2 + bc);
        s += a; q += a*a;
    }
    red[wv][c] = s; red[wv][64+c] = q;
    __syncthreads();
    if (tid < 128) {
        float t = red[0][tid]+red[1][tid]+red[2][tid]+red[3][tid];
        atomicAdd(&gstat[(blockIdx.x & (NREP-1))*128 + tid], t);
    }
}

// ---------- a2: 16 lanes per edge, coalesced k-row gather, butterfly reduce ----------
// grid NE/16 = 32768 blocks
__global__ __launch_bounds__(256) void k_edge2(
    const int* __restrict__ esrc, const float4* __restrict__ u4,
    const float* __restrict__ kbuf, const float* __restrict__ qbuf,
    const float* __restrict__ fP,
    const float* __restrict__ p2w, const float* __restrict__ p2b,
    const float* __restrict__ fW1,
    const float* __restrict__ w1w, const float* __restrict__ w1bias,
    float* __restrict__ a2out, float* __restrict__ gstat)
{
    __shared__ float4 w1L[128];     // w1L[jout*16 + t] = w1w[jout*64 + 4t .. +3]
    __shared__ float red[4][16];
    const int tid = threadIdx.x;
    if (tid < 128) w1L[tid] = ((const float4*)w1w)[tid];
    __syncthreads();

    const int t = tid & 15;
    const int e = blockIdx.x*16 + (tid >> 4);
    const int sj = esrc[e]; const int d = e >> 4;
    const int c0 = 4*t;
    const float scp0=fP[0], scp1=fP[1], scp2=fP[2];
    const float shp0=fP[64], shp1=fP[65], shp2=fP[66];
    float4 uu = u4[e];
    const float r0 = frelu(uu.x*scp0+shp0);
    const float r1 = frelu(uu.y*scp1+shp1);
    const float r2 = frelu(uu.z*scp2+shp2);
    float4 k4 = ((const float4*)(kbuf + (size_t)sj*CH))[t];
    float4 q4 = ((const float4*)(qbuf + (size_t)d*CH))[t];
    float4 pb4 = ((const float4*)p2b)[t];
    float4 sc4 = ((const float4*)fW1)[t];
    float4 sh4 = ((const float4*)(fW1+64))[t];
    float pw[12];
    #pragma unroll
    for (int k2=0;k2<12;++k2) pw[k2] = p2w[c0*3+k2];
    const float b0 = frelu((k4.x - q4.x + r0*pw[0]+r1*pw[1]+r2*pw[2] +pb4.x)*sc4.x+sh4.x);
    const float b1 = frelu((k4.y - q4.y + r0*pw[3]+r1*pw[4]+r2*pw[5] +pb4.y)*sc4.y+sh4.y);
    const float b2 = frelu((k4.z - q4.z + r0*pw[6]+r1*pw[7]+r2*pw[8] +pb4.z)*sc4.z+sh4.z);
    const float b3 = frelu((k4.w - q4.w + r0*pw[9]+r1*pw[10]+r2*pw[11]+pb4.w)*sc4.w+sh4.w);
    float p[8];
    #pragma unroll
    for (int j=0;j<8;++j){
        float4 w4 = w1L[j*16 + t];
        p[j] = b0*w4.x + b1*w4.y + b2*w4.z + b3*w4.w;
    }
    // butterfly over the 16-lane edge group
    #pragma unroll
    for (int msk=8;msk>=1;msk>>=1){
        #pragma unroll
        for (int j=0;j<8;++j) p[j] += __shfl_xor(p[j], msk);
    }
    float a2f[8], sq[8];
    #pragma unroll
    for (int j=0;j<8;++j){ a2f[j] = p[j] + w1bias[j]; sq[j] = a2f[j]*a2f[j]; }
    if (t < 2) {
        float4 w = (t==0) ? make_float4(a2f[0],a2f[1],a2f[2],a2f[3])
                          : make_float4(a2f[4],a2f[5],a2f[6],a2f[7]);
        ((float4*)a2out)[(size_t)e*2 + t] = w;
    }
    // cross-group (wave) reduce
    #pragma unroll
    for (int msk=32;msk>=16;msk>>=1){
        #pragma unroll
        for (int j=0;j<8;++j){ a2f[j]+=__shfl_xor(a2f[j],msk); sq[j]+=__shfl_xor(sq[j],msk); }
    }
    const int wv = tid>>6;
    if ((tid&63)==0){
        #pragma unroll
        for (int j=0;j<8;++j){ red[wv][j]=a2f[j]; red[wv][8+j]=sq[j]; }
    }
    __syncthreads();
    if (tid < 16) {
        float tt = red[0][tid]+red[1][tid]+red[2][tid]+red[3][tid];
        int dstc = (tid<8) ? tid : (64 + tid - 8);
        atomicAdd(&gstat[(blockIdx.x & (NREP-1))*128 + dstc], tt);
    }
}

// ---------- bn_w2 + w2 matmul + softmax (A), channel-owner aggregation (B) + bn2 stats ----------
__global__ __launch_bounds__(256) void k_attn(
    const int* __restrict__ esrc, const float4* __restrict__ u4,
    const float* __restrict__ vbuf, const float* __restrict__ a2buf,
    const float* __restrict__ fP,
    const float* __restrict__ p2w, const float* __restrict__ p2b,
    const float* __restrict__ fW2,
    const float* __restrict__ w2w, const float* __restrict__ w2bias,
    float* __restrict__ outbuf, float* __restrict__ gstat)
{
    __shared__ float red[4][128];
    __shared__ float att[256][8];
    __shared__ float rrL[256][4];
    __shared__ int   sjL[256];
    const int tid = threadIdx.x;
    const float scp0=fP[0], scp1=fP[1], scp2=fP[2];
    const float shp0=fP[64], shp1=fP[65], shp2=fP[66];

    const int t = tid & 15;
    const int i = blockIdx.x*16 + (tid>>4);
    const int e = i*KNN + t;
    const int sj = esrc[e];
    sjL[tid] = sj;
    {
        float4 uu = u4[e];
        rrL[tid][0] = frelu(uu.x*scp0+shp0);
        rrL[tid][1] = frelu(uu.y*scp1+shp1);
        rrL[tid][2] = frelu(uu.z*scp2+shp2);
    }
    // ---- phase A ----
    {
        const float4* a2v = (const float4*)a2buf;
        float4 aA = a2v[(size_t)e*2], aB = a2v[(size_t)e*2+1];
        float bb[8];
        bb[0]=frelu(aA.x*fW2[0]+fW2[64]); bb[1]=frelu(aA.y*fW2[1]+fW2[65]);
        bb[2]=frelu(aA.z*fW2[2]+fW2[66]); bb[3]=frelu(aA.w*fW2[3]+fW2[67]);
        bb[4]=frelu(aB.x*fW2[4]+fW2[68]); bb[5]=frelu(aB.y*fW2[5]+fW2[69]);
        bb[6]=frelu(aB.z*fW2[6]+fW2[70]); bb[7]=frelu(aB.w*fW2[7]+fW2[71]);
        float at[8];
        #pragma unroll
        for (int s=0;s<8;++s){
            float a3 = w2bias[s];
            #pragma unroll
            for (int u=0;u<8;++u) a3 += bb[u]*w2w[s*8+u];
            float m = a3;
            #pragma unroll
            for (int msk=8;msk>=1;msk>>=1) m = fmaxf(m, __shfl_xor(m,msk));
            float p = __expf(a3-m);
            float ssm = p;
            #pragma unroll
            for (int msk=8;msk>=1;msk>>=1) ssm += __shfl_xor(ssm,msk);
            at[s] = p/ssm;
        }
        ((float4*)att[tid])[0] = make_float4(at[0],at[1],at[2],at[3]);
        ((float4*)att[tid])[1] = make_float4(at[4],at[5],at[6],at[7]);
    }
    __syncthreads();
    // ---- phase B: thread owns channels 4t..4t+3 of point i ----
    const int base = (tid>>4)*16;
    const int c0 = 4*t;
    const int ho = (t&1);
    float pw[12], pbv[4];
    #pragma unroll
    for (int k2=0;k2<12;++k2) pw[k2] = p2w[c0*3+k2];
    #pragma unroll
    for (int k2=0;k2<4;++k2)  pbv[k2] = p2b[c0+k2];
    float4 res = make_float4(0,0,0,0);
    #pragma unroll 4
    for (int n=0; n<16; ++n){
        const int sjn = sjL[base+n];
        float4 v4 = ((const float4*)(vbuf + (size_t)sjn*CH))[t];
        const float rr0 = rrL[base+n][0], rr1 = rrL[base+n][1], rr2 = rrL[base+n][2];
        float4 a4 = ((const float4*)att[base+n])[ho];
        res.x += a4.x*(v4.x + rr0*pw[0]+rr1*pw[1]+rr2*pw[2]+pbv[0]);
        res.y += a4.y*(v4.y + rr0*pw[3]+rr1*pw[4]+rr2*pw[5]+pbv[1]);
        res.z += a4.z*(v4.z + rr0*pw[6]+rr1*pw[7]+rr2*pw[8]+pbv[2]);
        res.w += a4.w*(v4.w + rr0*pw[9]+rr1*pw[10]+rr2*pw[11]+pbv[3]);
    }
    ((float4*)outbuf)[(size_t)i*16 + t] = res;

    // fused bn2 stats
    float4 sq = make_float4(res.x*res.x, res.y*res.y, res.z*res.z, res.w*res.w);
    #pragma unroll
    for (int msk=32;msk>=16;msk>>=1){
        res.x+=__shfl_xor(res.x,msk); res.y+=__shfl_xor(res.y,msk);
        res.z+=__shfl_xor(res.z,msk); res.w+=__shfl_xor(res.w,msk);
        sq.x+=__shfl_xor(sq.x,msk);  sq.y+=__shfl_xor(sq.y,msk);
        sq.z+=__shfl_xor(sq.z,msk);  sq.w+=__shfl_xor(sq.w,msk);
    }
    const int wv = tid>>6;
    if ((tid&63) < 16){
        red[wv][t*4+0]=res.x; red[wv][t*4+1]=res.y; red[wv][t*4+2]=res.z; red[wv][t*4+3]=res.w;
        red[wv][64+t*4+0]=sq.x; red[wv][64+t*4+1]=sq.y; red[wv][64+t*4+2]=sq.z; red[wv][64+t*4+3]=sq.w;
    }
    __syncthreads();
    if (tid < 128) {
        float tt = red[0][tid]+red[1][tid]+red[2][tid]+red[3][tid];
        atomicAdd(&gstat[(blockIdx.x & (NREP-1))*128 + tid], tt);
    }
}

// ---------- final = relu(bn3(h3) + x_skip) ----------
__global__ __launch_bounds__(256) void k_final(
    const float* __restrict__ h3, const float* __restrict__ x,
    const float* __restrict__ fbn, float* __restrict__ out)
{
    const int tid = threadIdx.x;
    const int gi = blockIdx.x*256 + tid;
    const int c0 = (gi & 15)*4;
    float sc0=fbn[c0],sc1=fbn[c0+1],sc2=fbn[c0+2],sc3=fbn[c0+3];
    float sh0=fbn[64+c0],sh1=fbn[64+c0+1],sh2=fbn[64+c0+2],sh3=fbn[64+c0+3];
    float4 h = ((const float4*)h3)[gi];
    float4 xv = ((const float4*)x)[gi];
    float4 o;
    o.x = fmaxf(h.x*sc0+sh0+xv.x, 0.f);
    o.y = fmaxf(h.y*sc1+sh1+xv.y, 0.f);
    o.z = fmaxf(h.z*sc2+sh2+xv.z, 0.f);
    o.w = fmaxf(h.w*sc3+sh3+xv.w, 0.f);
    ((float4*)out)[gi] = o;
}

extern "C" void kernel_launch(void* const* d_in, const int* in_sizes, int n_in,
                              void* d_out, int out_size, void* d_ws, size_t ws_size,
                              hipStream_t stream) {
    (void)in_sizes; (void)n_in; (void)out_size; (void)ws_size;
    const float* pos   = (const float*)d_in[0];
    const float* x     = (const float*)d_in[1];
    const float* W1    = (const float*)d_in[2];
    const float* Wk    = (const float*)d_in[3];
    const float* bk    = (const float*)d_in[4];
    const float* Wq    = (const float*)d_in[5];
    const float* bq    = (const float*)d_in[6];
    const float* Wv    = (const float*)d_in[7];
    const float* bv    = (const float*)d_in[8];
    const float* p1w   = (const float*)d_in[9];
    const float* p1b   = (const float*)d_in[10];
    const float* pg    = (const float*)d_in[11];
    const float* pb    = (const float*)d_in[12];
    const float* p2w   = (const float*)d_in[13];
    const float* p2b   = (const float*)d_in[14];
    const float* w1g   = (const float*)d_in[15];
    const float* w1bb  = (const float*)d_in[16];
    const float* w1w   = (const float*)d_in[17];
    const float* w1bias= (const float*)d_in[18];
    const float* w2g   = (const float*)d_in[19];
    const float* w2bb  = (const float*)d_in[20];
    const float* w2w   = (const float*)d_in[21];
    const float* w2bias= (const float*)d_in[22];
    const float* W3    = (const float*)d_in[23];
    const float* bn1g  = (const float*)d_in[24];
    const float* bn1b  = (const float*)d_in[25];
    const float* bn2g  = (const float*)d_in[26];
    const float* bn2b  = (const float*)d_in[27];
    const float* bn3g  = (const float*)d_in[28];
    const float* bn3b  = (const float*)d_in[29];
    const int*   ei    = (const int*)d_in[30];
    float* ws  = (float*)d_ws;
    float* out = (float*)d_out;

    hipMemsetAsync(ws, 0, STATS_FLOATS*sizeof(float), stream);

    // u precompute + p-bn stats
    k_pstats_u<<<2048, 256, 0, stream>>>(pos, ei, p1w, p1b,
        (float4*)(ws+OFF_U), ws+G_P);
    // t1 = x @ W1^T + bn1 stats
    k_gemm64<<<256, 256, 0, stream>>>(x, W1, ws+OFF_T1, nullptr, 0, ws+G_BN1);
    // finalize P and BN1
    k_fin<<<2, 128, 0, stream>>>(ws+G_P, 1.f/NE, pg, pb, ws+F_P, 3,
                                 ws+G_BN1, 1.f/NPTS, bn1g, bn1b, ws+F_BN1, 64);
    // k,q,v
    k_kqv<<<768, 256, 0, stream>>>(ws+OFF_T1, Wk, bk, Wq, bq, Wv, bv,
        ws+F_BN1, ws+OFF_K, ws+OFF_Q, ws+OFF_V);
    // w_bn1 stats
    k_edge1<<<8192, 256, 0, stream>>>(ei, (const float4*)(ws+OFF_U),
        ws+OFF_K, ws+OFF_Q, ws+F_P, p2w, p2b, ws+G_W1);
    // finalize W1
    k_fin<<<1, 128, 0, stream>>>(ws+G_W1, 1.f/NE, w1g, w1bb, ws+F_W1, 64,
                                 nullptr, 0.f, nullptr, nullptr, nullptr, 0);
    // a2 + w_bn2 stats
    k_edge2<<<32768, 256, 0, stream>>>(ei, (const float4*)(ws+OFF_U),
        ws+OFF_K, ws+OFF_Q, ws+F_P, p2w, p2b,
        ws+F_W1, w1w, w1bias, ws+OFF_A2, ws+G_W2);
    // finalize W2
    k_fin<<<1, 128, 0, stream>>>(ws+G_W2, 1.f/NE, w2g, w2bb, ws+F_W2, 8,
                                 nullptr, 0.f, nullptr, nullptr, nullptr, 0);
    // softmax + aggregate + bn2 stats
    k_attn<<<2048, 256, 0, stream>>>(ei, (const float4*)(ws+OFF_U),
        ws+OFF_V, ws+OFF_A2, ws+F_P, p2w, p2b,
        ws+F_W2, w2w, w2bias, ws+OFF_OUT, ws+G_BN2);
    // finalize BN2
    k_fin<<<1, 128, 0, stream>>>(ws+G_BN2, 1.f/NPTS, bn2g, bn2b, ws+F_BN2, 64,
                                 nullptr, 0.f, nullptr, nullptr, nullptr, 0);
    // h3 = relu(bn2(out)) @ W3^T + bn3 stats
    k_gemm64<<<256, 256, 0, stream>>>(ws+OFF_OUT, W3, ws+OFF_H3,
        ws+F_BN2, 1, ws+G_BN3);
    // finalize BN3
    k_fin<<<1, 128, 0, stream>>>(ws+G_BN3, 1.f/NPTS, bn3g, bn3b, ws+F_BN3, 64,
                                 nullptr, 0.f, nullptr, nullptr, nullptr, 0);
    // final
    k_final<<<2048, 256, 0, stream>>>(ws+OFF_H3, x, ws+F_BN3, out);
}

// Round 9
// 280.952 us; speedup vs baseline: 2.0843x; 1.3214x over previous
//
#include <hip/hip_runtime.h>

#define NPTS 32768
#define CH 64
#define KNN 16
#define NE (NPTS*KNN)
#define EPS 1e-5f
#define NREP 32

// raw stats groups: NREP replicas x 128 floats; sums at [c], sumsq at [64+c]
#define G_P   0
#define G_BN1 (1*NREP*128)
#define G_W1  (2*NREP*128)
#define G_W2  (3*NREP*128)
#define G_BN2 (4*NREP*128)
#define G_BN3 (5*NREP*128)
#define STATS_FLOATS (6*NREP*128)

// finalized scale/shift: 128 floats each: [sc 0..63][sh 64..127]
#define F_P   (STATS_FLOATS + 0*128)
#define F_BN1 (STATS_FLOATS + 1*128)
#define F_W1  (STATS_FLOATS + 2*128)
#define F_W2  (STATS_FLOATS + 3*128)
#define F_BN2 (STATS_FLOATS + 4*128)
#define F_BN3 (STATS_FLOATS + 5*128)

#define OFF_T1  (STATS_FLOATS + 1024)
#define SZ_NC   (NPTS*CH)
// bf16 buffers (sizes in float units: NPTS*32 uints each)
#define OFF_K   (OFF_T1 + SZ_NC)
#define OFF_Q   (OFF_K + NPTS*32)
#define OFF_V   (OFF_Q + NPTS*32)
#define OFF_A2  (OFF_V + NPTS*32)      /* NE*4 uints (8 bf16/edge) */
#define OFF_OUT (OFF_A2 + NE*4)
#define OFF_U   (OFF_OUT + SZ_NC)      /* NE*4 floats; aliased with H3 */
#define OFF_H3  OFF_U

typedef unsigned int uint;

__device__ __forceinline__ float frelu(float x){ return fmaxf(x, 0.f); }
__device__ __forceinline__ float bflo(uint u){ return __uint_as_float(u<<16); }
__device__ __forceinline__ float bfhi(uint u){ return __uint_as_float(u & 0xffff0000u); }
__device__ __forceinline__ uint bfpack(float lo, float hi){
    uint a = __float_as_uint(lo), b = __float_as_uint(hi);
    a = (a + 0x7fffu + ((a>>16)&1u)) >> 16;
    b = ((b + 0x7fffu + ((b>>16)&1u)) >> 16) << 16;
    return a | b;
}

// ---------- finalize up to two stats groups -> [sc|sh] ----------
__global__ __launch_bounds__(128) void k_fin(
    const float* __restrict__ gA, float invA, const float* __restrict__ gmA,
    const float* __restrict__ btA, float* __restrict__ outA, int nchA,
    const float* __restrict__ gB, float invB, const float* __restrict__ gmB,
    const float* __restrict__ btB, float* __restrict__ outB, int nchB)
{
    __shared__ float s_tmp[128];
    const int tid = threadIdx.x;
    const float* g; float inv; const float* gm; const float* bt; float* o; int nch;
    if (blockIdx.x == 0) { g=gA; inv=invA; gm=gmA; bt=btA; o=outA; nch=nchA; }
    else { if (!outB) return; g=gB; inv=invB; gm=gmB; bt=btB; o=outB; nch=nchB; }
    float t = 0.f;
    #pragma unroll
    for (int r=0;r<NREP;++r) t += g[r*128+tid];
    s_tmp[tid] = t;
    __syncthreads();
    if (tid < 64) {
        if (tid < nch) {
            float m = s_tmp[tid]*inv;
            float v = s_tmp[64+tid]*inv - m*m;
            float s = gm[tid]*rsqrtf(v+EPS);
            o[tid] = s; o[64+tid] = bt[tid] - m*s;
        } else { o[tid]=0.f; o[64+tid]=0.f; }
    }
}

// ---------- u = rel @ p1_w^T + p1_b per edge (stored), plus p-bn stats ----------
__global__ __launch_bounds__(256) void k_pstats_u(
    const float* __restrict__ pos, const int* __restrict__ esrc,
    const float* __restrict__ p1w, const float* __restrict__ p1b,
    float4* __restrict__ u4, float* __restrict__ gstat)
{
    __shared__ float red[4][6];
    const int tid = threadIdx.x;
    const float w0=p1w[0],w1=p1w[1],w2=p1w[2],w3=p1w[3],w4=p1w[4],w5=p1w[5],w6=p1w[6],w7=p1w[7],w8=p1w[8];
    const float b0=p1b[0],b1=p1b[1],b2=p1b[2];
    const int e = blockIdx.x*256 + tid;
    const int sj = esrc[e]; const int d = e >> 4;
    float ax = pos[3*sj]-pos[3*d], ay = pos[3*sj+1]-pos[3*d+1], az = pos[3*sj+2]-pos[3*d+2];
    float u0 = w0*ax+w1*ay+w2*az+b0;
    float u1 = w3*ax+w4*ay+w5*az+b1;
    float u2 = w6*ax+w7*ay+w8*az+b2;
    u4[e] = make_float4(u0,u1,u2,0.f);
    float s0=u0,s1=u1,s2=u2,q0=u0*u0,q1=u1*u1,q2=u2*u2;
    #pragma unroll
    for (int m=32;m>=1;m>>=1){
        s0+=__shfl_xor(s0,m); s1+=__shfl_xor(s1,m); s2+=__shfl_xor(s2,m);
        q0+=__shfl_xor(q0,m); q1+=__shfl_xor(q1,m); q2+=__shfl_xor(q2,m);
    }
    const int wv = tid>>6;
    if ((tid&63)==0){ red[wv][0]=s0; red[wv][1]=s1; red[wv][2]=s2;
                      red[wv][3]=q0; red[wv][4]=q1; red[wv][5]=q2; }
    __syncthreads();
    float* g = gstat + (blockIdx.x & (NREP-1))*128;
    if (tid < 3)      atomicAdd(&g[tid],        red[0][tid]+red[1][tid]+red[2][tid]+red[3][tid]);
    else if (tid < 6) atomicAdd(&g[64+(tid-3)], red[0][tid]+red[1][tid]+red[2][tid]+red[3][tid]);
}

// ---------- [N,64]@W^T f32 out; 2 rows/thread x 16 out-ch; bounded inner loop ----------
__global__ __launch_bounds__(256) void k_gemm64(
    const float* __restrict__ in, const float* __restrict__ W,
    float* __restrict__ out,
    const float* __restrict__ fbn, int applyBn,
    float* __restrict__ gstat)
{
    __shared__ float Wt[CH*16];
    __shared__ float4 fL[32];
    __shared__ float red[4][32];
    const int tid = threadIdx.x;
    const int wv = tid >> 6;
    const int rb = blockIdx.x >> 2;
    const int c0 = (blockIdx.x & 3)*16;
    #pragma unroll
    for (int ch=0; ch<4; ++ch){
        const int idx = ch*256 + tid;
        Wt[idx] = W[(size_t)(c0 + (idx & 15))*CH + (idx >> 4)];
    }
    if (applyBn && tid < 32) fL[tid] = ((const float4*)fbn)[tid];
    __syncthreads();

    const int row0 = rb*512 + tid;
    const float4* iv0 = (const float4*)(in + (size_t)row0*CH);
    const float4* iv1 = (const float4*)(in + (size_t)(row0+256)*CH);
    const float4* Wt4 = (const float4*)Wt;
    float4 A0=make_float4(0,0,0,0),A1=A0,A2=A0,A3=A0;
    float4 B0=A0,B1=A0,B2=A0,B3=A0;
    #pragma unroll 1
    for (int jj=0;jj<16;++jj){
        float4 x0 = iv0[jj], x1 = iv1[jj];
        if (applyBn){
            float4 s4 = fL[jj], h4 = fL[16+jj];
            x0.x=frelu(x0.x*s4.x+h4.x); x0.y=frelu(x0.y*s4.y+h4.y);
            x0.z=frelu(x0.z*s4.z+h4.z); x0.w=frelu(x0.w*s4.w+h4.w);
            x1.x=frelu(x1.x*s4.x+h4.x); x1.y=frelu(x1.y*s4.y+h4.y);
            x1.z=frelu(x1.z*s4.z+h4.z); x1.w=frelu(x1.w*s4.w+h4.w);
        }
        const float4* wb = &Wt4[jj*16];
        #define MSTEP(xa, xb, base) { \
            float4 w_0=wb[(base)+0], w_1=wb[(base)+1], w_2=wb[(base)+2], w_3=wb[(base)+3]; \
            A0.x+=(xa)*w_0.x; A0.y+=(xa)*w_0.y; A0.z+=(xa)*w_0.z; A0.w+=(xa)*w_0.w; \
            A1.x+=(xa)*w_1.x; A1.y+=(xa)*w_1.y; A1.z+=(xa)*w_1.z; A1.w+=(xa)*w_1.w; \
            A2.x+=(xa)*w_2.x; A2.y+=(xa)*w_2.y; A2.z+=(xa)*w_2.z; A2.w+=(xa)*w_2.w; \
            A3.x+=(xa)*w_3.x; A3.y+=(xa)*w_3.y; A3.z+=(xa)*w_3.z; A3.w+=(xa)*w_3.w; \
            B0.x+=(xb)*w_0.x; B0.y+=(xb)*w_0.y; B0.z+=(xb)*w_0.z; B0.w+=(xb)*w_0.w; \
            B1.x+=(xb)*w_1.x; B1.y+=(xb)*w_1.y; B1.z+=(xb)*w_1.z; B1.w+=(xb)*w_1.w; \
            B2.x+=(xb)*w_2.x; B2.y+=(xb)*w_2.y; B2.z+=(xb)*w_2.z; B2.w+=(xb)*w_2.w; \
            B3.x+=(xb)*w_3.x; B3.y+=(xb)*w_3.y; B3.z+=(xb)*w_3.z; B3.w+=(xb)*w_3.w; }
        MSTEP(x0.x, x1.x, 0) MSTEP(x0.y, x1.y, 4) MSTEP(x0.z, x1.z, 8) MSTEP(x0.w, x1.w, 12)
        #undef MSTEP
    }
    float4* ov0 = (float4*)(out + (size_t)row0*CH + c0);
    float4* ov1 = (float4*)(out + (size_t)(row0+256)*CH + c0);
    ov0[0]=A0; ov0[1]=A1; ov0[2]=A2; ov0[3]=A3;
    ov1[0]=B0; ov1[1]=B1; ov1[2]=B2; ov1[3]=B3;
    #define STATQ(q, A, B) { \
        float4 s = make_float4(A.x+B.x, A.y+B.y, A.z+B.z, A.w+B.w); \
        float4 sq = make_float4(A.x*A.x+B.x*B.x, A.y*A.y+B.y*B.y, A.z*A.z+B.z*B.z, A.w*A.w+B.w*B.w); \
        _Pragma("unroll") \
        for (int m=32;m>=1;m>>=1){ \
            s.x+=__shfl_xor(s.x,m); s.y+=__shfl_xor(s.y,m); \
            s.z+=__shfl_xor(s.z,m); s.w+=__shfl_xor(s.w,m); \
            sq.x+=__shfl_xor(sq.x,m); sq.y+=__shfl_xor(sq.y,m); \
            sq.z+=__shfl_xor(sq.z,m); sq.w+=__shfl_xor(sq.w,m); } \
        if ((tid&63)==0){ \
            red[wv][q*4+0]=s.x; red[wv][q*4+1]=s.y; red[wv][q*4+2]=s.z; red[wv][q*4+3]=s.w; \
            red[wv][16+q*4+0]=sq.x; red[wv][16+q*4+1]=sq.y; red[wv][16+q*4+2]=sq.z; red[wv][16+q*4+3]=sq.w; } }
    STATQ(0, A0, B0) STATQ(1, A1, B1) STATQ(2, A2, B2) STATQ(3, A3, B3)
    #undef STATQ
    __syncthreads();
    if (tid < 32) {
        float t = red[0][tid]+red[1][tid]+red[2][tid]+red[3][tid];
        int dstc = (tid<16) ? (c0+tid) : (64 + c0 + (tid-16));
        atomicAdd(&gstat[(blockIdx.x & (NREP-1))*128 + dstc], t);
    }
}

// ---------- k/q/v: grid 768; bf16-packed outputs ----------
__global__ __launch_bounds__(256) void k_kqv(
    const float* __restrict__ t1,
    const float* __restrict__ Wk, const float* __restrict__ bk,
    const float* __restrict__ Wq, const float* __restrict__ bq,
    const float* __restrict__ Wv, const float* __restrict__ bv,
    const float* __restrict__ fbn,
    uint* __restrict__ kout, uint* __restrict__ qout, uint* __restrict__ vout)
{
    __shared__ float Wt[CH*16];
    __shared__ float4 fL[32];
    __shared__ float4 bias4[4];
    const int tid = threadIdx.x;
    const int m = blockIdx.x / 256;
    const int rem = blockIdx.x & 255;
    const int rb = rem >> 2;
    const int c0 = (rem & 3)*16;
    const float* W  = (m==0) ? Wk : (m==1 ? Wq : Wv);
    const float* bs = (m==0) ? bk : (m==1 ? bq : bv);
    uint* o         = (m==0) ? kout : (m==1 ? qout : vout);
    #pragma unroll
    for (int ch=0; ch<4; ++ch){
        const int idx = ch*256 + tid;
        Wt[idx] = W[(size_t)(c0 + (idx & 15))*CH + (idx >> 4)];
    }
    if (tid < 32) fL[tid] = ((const float4*)fbn)[tid];
    if (tid < 4)  bias4[tid] = ((const float4*)(bs + c0))[tid];
    __syncthreads();

    const int row0 = rb*512 + tid;
    const float4* iv0 = (const float4*)(t1 + (size_t)row0*CH);
    const float4* iv1 = (const float4*)(t1 + (size_t)(row0+256)*CH);
    const float4* Wt4 = (const float4*)Wt;
    float4 A0=bias4[0],A1=bias4[1],A2=bias4[2],A3=bias4[3];
    float4 B0=bias4[0],B1=bias4[1],B2=bias4[2],B3=bias4[3];
    #pragma unroll 1
    for (int jj=0;jj<16;++jj){
        float4 x0 = iv0[jj], x1 = iv1[jj];
        float4 s4 = fL[jj], h4 = fL[16+jj];
        x0.x=frelu(x0.x*s4.x+h4.x); x0.y=frelu(x0.y*s4.y+h4.y);
        x0.z=frelu(x0.z*s4.z+h4.z); x0.w=frelu(x0.w*s4.w+h4.w);
        x1.x=frelu(x1.x*s4.x+h4.x); x1.y=frelu(x1.y*s4.y+h4.y);
        x1.z=frelu(x1.z*s4.z+h4.z); x1.w=frelu(x1.w*s4.w+h4.w);
        const float4* wb = &Wt4[jj*16];
        #define MSTEP(xa, xb, base) { \
            float4 w_0=wb[(base)+0], w_1=wb[(base)+1], w_2=wb[(base)+2], w_3=wb[(base)+3]; \
            A0.x+=(xa)*w_0.x; A0.y+=(xa)*w_0.y; A0.z+=(xa)*w_0.z; A0.w+=(xa)*w_0.w; \
            A1.x+=(xa)*w_1.x; A1.y+=(xa)*w_1.y; A1.z+=(xa)*w_1.z; A1.w+=(xa)*w_1.w; \
            A2.x+=(xa)*w_2.x; A2.y+=(xa)*w_2.y; A2.z+=(xa)*w_2.z; A2.w+=(xa)*w_2.w; \
            A3.x+=(xa)*w_3.x; A3.y+=(xa)*w_3.y; A3.z+=(xa)*w_3.z; A3.w+=(xa)*w_3.w; \
            B0.x+=(xb)*w_0.x; B0.y+=(xb)*w_0.y; B0.z+=(xb)*w_0.z; B0.w+=(xb)*w_0.w; \
            B1.x+=(xb)*w_1.x; B1.y+=(xb)*w_1.y; B1.z+=(xb)*w_1.z; B1.w+=(xb)*w_1.w; \
            B2.x+=(xb)*w_2.x; B2.y+=(xb)*w_2.y; B2.z+=(xb)*w_2.z; B2.w+=(xb)*w_2.w; \
            B3.x+=(xb)*w_3.x; B3.y+=(xb)*w_3.y; B3.z+=(xb)*w_3.z; B3.w+=(xb)*w_3.w; }
        MSTEP(x0.x, x1.x, 0) MSTEP(x0.y, x1.y, 4) MSTEP(x0.z, x1.z, 8) MSTEP(x0.w, x1.w, 12)
        #undef MSTEP
    }
    uint4 pa, pb_;
    pa.x = bfpack(A0.x,A0.y); pa.y = bfpack(A0.z,A0.w);
    pa.z = bfpack(A1.x,A1.y); pa.w = bfpack(A1.z,A1.w);
    pb_.x = bfpack(A2.x,A2.y); pb_.y = bfpack(A2.z,A2.w);
    pb_.z = bfpack(A3.x,A3.y); pb_.w = bfpack(A3.z,A3.w);
    uint4* o0 = (uint4*)(o + (size_t)row0*32 + (c0>>1));
    o0[0]=pa; o0[1]=pb_;
    pa.x = bfpack(B0.x,B0.y); pa.y = bfpack(B0.z,B0.w);
    pa.z = bfpack(B1.x,B1.y); pa.w = bfpack(B1.z,B1.w);
    pb_.x = bfpack(B2.x,B2.y); pb_.y = bfpack(B2.z,B2.w);
    pb_.z = bfpack(B3.x,B3.y); pb_.w = bfpack(B3.z,B3.w);
    uint4* o1 = (uint4*)(o + (size_t)(row0+256)*32 + (c0>>1));
    o1[0]=pa; o1[1]=pb_;
}

// ---------- w_bn1 stats over apre = k[src]-q[dst]+delta (lane = channel, bf16 k/q) ----------
__global__ __launch_bounds__(256) void k_edge1(
    const int* __restrict__ esrc, const float4* __restrict__ u4,
    const unsigned short* __restrict__ kbuf, const unsigned short* __restrict__ qbuf,
    const float* __restrict__ fP,
    const float* __restrict__ p2w, const float* __restrict__ p2b,
    float* __restrict__ gstat)
{
    __shared__ float red[4][128];
    const int tid = threadIdx.x;
    const int c = tid & 63, wv = tid >> 6;
    const float scp0=fP[0], scp1=fP[1], scp2=fP[2];
    const float shp0=fP[64], shp1=fP[65], shp2=fP[66];
    const float w0 = p2w[c*3+0], w1 = p2w[c*3+1], w2 = p2w[c*3+2], bc = p2b[c];

    const int gw = blockIdx.x*4 + wv;      // 32768 waves
    const int chunk = NE/32768;            // 16 edges/wave
    const int e0 = gw*chunk;
    float s=0.f, q=0.f;
    #pragma unroll 4
    for (int e = e0; e < e0+chunk; ++e) {
        int sj = esrc[e]; int d = e >> 4;
        float4 uu = u4[e];
        float r0 = frelu(uu.x*scp0+shp0);
        float r1 = frelu(uu.y*scp1+shp1);
        float r2 = frelu(uu.z*scp2+shp2);
        float kv = __uint_as_float(((uint)kbuf[(size_t)sj*CH+c])<<16);
        float qv = __uint_as_float(((uint)qbuf[(size_t)d*CH+c])<<16);
        float a = kv - qv + (r0*w0 + r1*w1 + r2*w2 + bc);
        s += a; q += a*a;
    }
    red[wv][c] = s; red[wv][64+c] = q;
    __syncthreads();
    if (tid < 128) {
        float t = red[0][tid]+red[1][tid]+red[2][tid]+red[3][tid];
        atomicAdd(&gstat[(blockIdx.x & (NREP-1))*128 + tid], t);
    }
}

// ---------- a2 = relu(bn_w1(apre))@w1^T+b1 ; thread = edge; bf16 k/q in, bf16 a2 out ----------
__global__ __launch_bounds__(256) void k_edge2(
    const int* __restrict__ esrc, const float4* __restrict__ u4,
    const uint* __restrict__ kbuf, const uint* __restrict__ qbuf,
    const float* __restrict__ fP,
    const float* __restrict__ p2w, const float* __restrict__ p2b,
    const float* __restrict__ fW1,
    const float* __restrict__ w1w, const float* __restrict__ w1bias,
    uint* __restrict__ a2out, float* __restrict__ gstat)
{
    __shared__ float red[4][16];
    const int tid = threadIdx.x;
    const float scp0=fP[0], scp1=fP[1], scp2=fP[2];
    const float shp0=fP[64], shp1=fP[65], shp2=fP[66];

    const int e = blockIdx.x*256 + tid;    // 2048 blocks, one edge/thread
    const int sj = esrc[e]; const int d = e >> 4;
    float4 uu = u4[e];
    const float r0 = frelu(uu.x*scp0+shp0);
    const float r1 = frelu(uu.y*scp1+shp1);
    const float r2 = frelu(uu.z*scp2+shp2);
    const uint4* kv = (const uint4*)(kbuf + (size_t)sj*32);
    const uint4* qv = (const uint4*)(qbuf + (size_t)d*32);
    float a2a[8];
    #pragma unroll
    for (int j=0;j<8;++j) a2a[j] = w1bias[j];
    #pragma unroll
    for (int cc=0; cc<8; ++cc) {
        uint4 ku = kv[cc], qu = qv[cc];
        const int c0 = cc*8;
        float kq[8];
        kq[0]=bflo(ku.x)-bflo(qu.x); kq[1]=bfhi(ku.x)-bfhi(qu.x);
        kq[2]=bflo(ku.y)-bflo(qu.y); kq[3]=bfhi(ku.y)-bfhi(qu.y);
        kq[4]=bflo(ku.z)-bflo(qu.z); kq[5]=bfhi(ku.z)-bfhi(qu.z);
        kq[6]=bflo(ku.w)-bflo(qu.w); kq[7]=bfhi(ku.w)-bfhi(qu.w);
        #pragma unroll
        for (int p=0;p<8;++p){
            const int c = c0+p;
            float b = frelu((kq[p] + r0*p2w[c*3]+r1*p2w[c*3+1]+r2*p2w[c*3+2]+p2b[c])*fW1[c]+fW1[64+c]);
            #pragma unroll
            for (int j=0;j<8;++j) a2a[j] += b*w1w[j*64+c];
        }
    }
    uint4 au;
    au.x = bfpack(a2a[0],a2a[1]); au.y = bfpack(a2a[2],a2a[3]);
    au.z = bfpack(a2a[4],a2a[5]); au.w = bfpack(a2a[6],a2a[7]);
    ((uint4*)a2out)[e] = au;
    float q8[8];
    #pragma unroll
    for (int j=0;j<8;++j) q8[j]=a2a[j]*a2a[j];
    #pragma unroll
    for (int m=32;m>=1;m>>=1){
        #pragma unroll
        for (int j=0;j<8;++j){ a2a[j]+=__shfl_xor(a2a[j],m); q8[j]+=__shfl_xor(q8[j],m); }
    }
    const int wv = tid>>6;
    if ((tid&63)==0){
        #pragma unroll
        for (int j=0;j<8;++j){ red[wv][j]=a2a[j]; red[wv][8+j]=q8[j]; }
    }
    __syncthreads();
    if (tid < 16) {
        float t = red[0][tid]+red[1][tid]+red[2][tid]+red[3][tid];
        int dstc = (tid<8) ? tid : (64 + tid - 8);
        atomicAdd(&gstat[(blockIdx.x & (NREP-1))*128 + dstc], t);
    }
}

// ---------- bn_w2 + w2 matvec + softmax (A), channel-owner aggregation (B) + bn2 stats ----------
__global__ __launch_bounds__(256) void k_attn(
    const int* __restrict__ esrc, const float4* __restrict__ u4,
    const uint* __restrict__ vbuf, const uint* __restrict__ a2buf,
    const float* __restrict__ fP,
    const float* __restrict__ p2w, const float* __restrict__ p2b,
    const float* __restrict__ fW2,
    const float* __restrict__ w2w, const float* __restrict__ w2bias,
    float* __restrict__ outbuf, float* __restrict__ gstat)
{
    __shared__ float red[4][128];
    __shared__ float att[256][8];
    __shared__ float rrL[256][4];
    __shared__ int   sjL[256];
    const int tid = threadIdx.x;
    const float scp0=fP[0], scp1=fP[1], scp2=fP[2];
    const float shp0=fP[64], shp1=fP[65], shp2=fP[66];

    const int t = tid & 15;
    const int i = blockIdx.x*16 + (tid>>4);
    const int e = i*KNN + t;
    const int sj = esrc[e];
    sjL[tid] = sj;
    {
        float4 uu = u4[e];
        rrL[tid][0] = frelu(uu.x*scp0+shp0);
        rrL[tid][1] = frelu(uu.y*scp1+shp1);
        rrL[tid][2] = frelu(uu.z*scp2+shp2);
    }
    // ---- phase A ----
    {
        uint4 au = ((const uint4*)a2buf)[e];
        float bb[8];
        bb[0]=frelu(bflo(au.x)*fW2[0]+fW2[64]); bb[1]=frelu(bfhi(au.x)*fW2[1]+fW2[65]);
        bb[2]=frelu(bflo(au.y)*fW2[2]+fW2[66]); bb[3]=frelu(bfhi(au.y)*fW2[3]+fW2[67]);
        bb[4]=frelu(bflo(au.z)*fW2[4]+fW2[68]); bb[5]=frelu(bfhi(au.z)*fW2[5]+fW2[69]);
        bb[6]=frelu(bflo(au.w)*fW2[6]+fW2[70]); bb[7]=frelu(bfhi(au.w)*fW2[7]+fW2[71]);
        float at[8];
        #pragma unroll
        for (int s=0;s<8;++s){
            float a3 = w2bias[s];
            #pragma unroll
            for (int u=0;u<8;++u) a3 += bb[u]*w2w[s*8+u];
            float m = a3;
            #pragma unroll
            for (int msk=8;msk>=1;msk>>=1) m = fmaxf(m, __shfl_xor(m,msk));
            float p = __expf(a3-m);
            float ssm = p;
            #pragma unroll
            for (int msk=8;msk>=1;msk>>=1) ssm += __shfl_xor(ssm,msk);
            at[s] = p/ssm;
        }
        ((float4*)att[tid])[0] = make_float4(at[0],at[1],at[2],at[3]);
        ((float4*)att[tid])[1] = make_float4(at[4],at[5],at[6],at[7]);
    }
    __syncthreads();
    // ---- phase B: thread owns channels 4t..4t+3 of point i ----
    const int base = (tid>>4)*16;
    const int c0 = 4*t;
    const int ho = (t&1);
    float pw[12], pbv[4];
    #pragma unroll
    for (int k2=0;k2<12;++k2) pw[k2] = p2w[c0*3+k2];
    #pragma unroll
    for (int k2=0;k2<4;++k2)  pbv[k2] = p2b[c0+k2];
    float4 res = make_float4(0,0,0,0);
    #pragma unroll 4
    for (int n=0; n<16; ++n){
        const int sjn = sjL[base+n];
        uint2 vv = ((const uint2*)(vbuf + (size_t)sjn*32))[t];
        const float v0=bflo(vv.x), v1=bfhi(vv.x), v2=bflo(vv.y), v3=bfhi(vv.y);
        const float rr0 = rrL[base+n][0], rr1 = rrL[base+n][1], rr2 = rrL[base+n][2];
        float4 a4 = ((const float4*)att[base+n])[ho];
        res.x += a4.x*(v0 + rr0*pw[0]+rr1*pw[1]+rr2*pw[2]+pbv[0]);
        res.y += a4.y*(v1 + rr0*pw[3]+rr1*pw[4]+rr2*pw[5]+pbv[1]);
        res.z += a4.z*(v2 + rr0*pw[6]+rr1*pw[7]+rr2*pw[8]+pbv[2]);
        res.w += a4.w*(v3 + rr0*pw[9]+rr1*pw[10]+rr2*pw[11]+pbv[3]);
    }
    ((float4*)outbuf)[(size_t)i*16 + t] = res;

    // fused bn2 stats
    float4 sq = make_float4(res.x*res.x, res.y*res.y, res.z*res.z, res.w*res.w);
    #pragma unroll
    for (int msk=32;msk>=16;msk>>=1){
        res.x+=__shfl_xor(res.x,msk); res.y+=__shfl_xor(res.y,msk);
        res.z+=__shfl_xor(res.z,msk); res.w+=__shfl_xor(res.w,msk);
        sq.x+=__shfl_xor(sq.x,msk);  sq.y+=__shfl_xor(sq.y,msk);
        sq.z+=__shfl_xor(sq.z,msk);  sq.w+=__shfl_xor(sq.w,msk);
    }
    const int wv = tid>>6;
    if ((tid&63) < 16){
        red[wv][t*4+0]=res.x; red[wv][t*4+1]=res.y; red[wv][t*4+2]=res.z; red[wv][t*4+3]=res.w;
        red[wv][64+t*4+0]=sq.x; red[wv][64+t*4+1]=sq.y; red[wv][64+t*4+2]=sq.z; red[wv][64+t*4+3]=sq.w;
    }
    __syncthreads();
    if (tid < 128) {
        float tt = red[0][tid]+red[1][tid]+red[2][tid]+red[3][tid];
        atomicAdd(&gstat[(blockIdx.x & (NREP-1))*128 + tid], tt);
    }
}

// ---------- final = relu(bn3(h3) + x_skip) ----------
__global__ __launch_bounds__(256) void k_final(
    const float* __restrict__ h3, const float* __restrict__ x,
    const float* __restrict__ fbn, float* __restrict__ out)
{
    const int tid = threadIdx.x;
    const int gi = blockIdx.x*256 + tid;
    const int c0 = (gi & 15)*4;
    float sc0=fbn[c0],sc1=fbn[c0+1],sc2=fbn[c0+2],sc3=fbn[c0+3];
    float sh0=fbn[64+c0],sh1=fbn[64+c0+1],sh2=fbn[64+c0+2],sh3=fbn[64+c0+3];
    float4 h = ((const float4*)h3)[gi];
    float4 xv = ((const float4*)x)[gi];
    float4 o;
    o.x = fmaxf(h.x*sc0+sh0+xv.x, 0.f);
    o.y = fmaxf(h.y*sc1+sh1+xv.y, 0.f);
    o.z = fmaxf(h.z*sc2+sh2+xv.z, 0.f);
    o.w = fmaxf(h.w*sc3+sh3+xv.w, 0.f);
    ((float4*)out)[gi] = o;
}

extern "C" void kernel_launch(void* const* d_in, const int* in_sizes, int n_in,
                              void* d_out, int out_size, void* d_ws, size_t ws_size,
                              hipStream_t stream) {
    (void)in_sizes; (void)n_in; (void)out_size; (void)ws_size;
    const float* pos   = (const float*)d_in[0];
    const float* x     = (const float*)d_in[1];
    const float* W1    = (const float*)d_in[2];
    const float* Wk    = (const float*)d_in[3];
    const float* bk    = (const float*)d_in[4];
    const float* Wq    = (const float*)d_in[5];
    const float* bq    = (const float*)d_in[6];
    const float* Wv    = (const float*)d_in[7];
    const float* bv    = (const float*)d_in[8];
    const float* p1w   = (const float*)d_in[9];
    const float* p1b   = (const float*)d_in[10];
    const float* pg    = (const float*)d_in[11];
    const float* pb    = (const float*)d_in[12];
    const float* p2w   = (const float*)d_in[13];
    const float* p2b   = (const float*)d_in[14];
    const float* w1g   = (const float*)d_in[15];
    const float* w1bb  = (const float*)d_in[16];
    const float* w1w   = (const float*)d_in[17];
    const float* w1bias= (const float*)d_in[18];
    const float* w2g   = (const float*)d_in[19];
    const float* w2bb  = (const float*)d_in[20];
    const float* w2w   = (const float*)d_in[21];
    const float* w2bias= (const float*)d_in[22];
    const float* W3    = (const float*)d_in[23];
    const float* bn1g  = (const float*)d_in[24];
    const float* bn1b  = (const float*)d_in[25];
    const float* bn2g  = (const float*)d_in[26];
    const float* bn2b  = (const float*)d_in[27];
    const float* bn3g  = (const float*)d_in[28];
    const float* bn3b  = (const float*)d_in[29];
    const int*   ei    = (const int*)d_in[30];
    float* ws  = (float*)d_ws;
    float* out = (float*)d_out;
    uint* kb = (uint*)(ws+OFF_K);
    uint* qb = (uint*)(ws+OFF_Q);
    uint* vb = (uint*)(ws+OFF_V);
    uint* a2b = (uint*)(ws+OFF_A2);

    hipMemsetAsync(ws, 0, STATS_FLOATS*sizeof(float), stream);

    // u precompute + p-bn stats
    k_pstats_u<<<2048, 256, 0, stream>>>(pos, ei, p1w, p1b,
        (float4*)(ws+OFF_U), ws+G_P);
    // t1 = x @ W1^T + bn1 stats
    k_gemm64<<<256, 256, 0, stream>>>(x, W1, ws+OFF_T1, nullptr, 0, ws+G_BN1);
    // finalize P and BN1
    k_fin<<<2, 128, 0, stream>>>(ws+G_P, 1.f/NE, pg, pb, ws+F_P, 3,
                                 ws+G_BN1, 1.f/NPTS, bn1g, bn1b, ws+F_BN1, 64);
    // k,q,v (bf16)
    k_kqv<<<768, 256, 0, stream>>>(ws+OFF_T1, Wk, bk, Wq, bq, Wv, bv,
        ws+F_BN1, kb, qb, vb);
    // w_bn1 stats
    k_edge1<<<8192, 256, 0, stream>>>(ei, (const float4*)(ws+OFF_U),
        (const unsigned short*)kb, (const unsigned short*)qb, ws+F_P, p2w, p2b, ws+G_W1);
    // finalize W1
    k_fin<<<1, 128, 0, stream>>>(ws+G_W1, 1.f/NE, w1g, w1bb, ws+F_W1, 64,
                                 nullptr, 0.f, nullptr, nullptr, nullptr, 0);
    // a2 + w_bn2 stats
    k_edge2<<<2048, 256, 0, stream>>>(ei, (const float4*)(ws+OFF_U),
        kb, qb, ws+F_P, p2w, p2b,
        ws+F_W1, w1w, w1bias, a2b, ws+G_W2);
    // finalize W2
    k_fin<<<1, 128, 0, stream>>>(ws+G_W2, 1.f/NE, w2g, w2bb, ws+F_W2, 8,
                                 nullptr, 0.f, nullptr, nullptr, nullptr, 0);
    // softmax + aggregate + bn2 stats
    k_attn<<<2048, 256, 0, stream>>>(ei, (const float4*)(ws+OFF_U),
        vb, a2b, ws+F_P, p2w, p2b,
        ws+F_W2, w2w, w2bias, ws+OFF_OUT, ws+G_BN2);
    // finalize BN2
    k_fin<<<1, 128, 0, stream>>>(ws+G_BN2, 1.f/NPTS, bn2g, bn2b, ws+F_BN2, 64,
                                 nullptr, 0.f, nullptr, nullptr, nullptr, 0);
    // h3 = relu(bn2(out)) @ W3^T + bn3 stats
    k_gemm64<<<256, 256, 0, stream>>>(ws+OFF_OUT, W3, ws+OFF_H3,
        ws+F_BN2, 1, ws+G_BN3);
    // finalize BN3
    k_fin<<<1, 128, 0, stream>>>(ws+G_BN3, 1.f/NPTS, bn3g, bn3b, ws+F_BN3, 64,
                                 nullptr, 0.f, nullptr, nullptr, nullptr, 0);
    // final
    k_final<<<2048, 256, 0, stream>>>(ws+OFF_H3, x, ws+F_BN3, out);
}